// Round 11
// baseline (345.288 us; speedup 1.0000x reference)
//
#include <hip/hip_runtime.h>
#include <hip/hip_fp16.h>
#include <math.h>

#define N_NODES 30000
#define E_EDGES 480000
#define VD      512
#define HID     32
#define BUCKET  3750   // rows per src-bucket: 3750 * 1KB = 3.75 MB < 4 MB per-XCD L2
#define K1_BLOCKS 512

// ws layout — BYTE-INTERVAL AUDIT (4-byte floats unless noted):
//   acc   floats [0, 30000)        = bytes [0, 120000)
//   deg   floats [30000, 60000)    = bytes [120000, 240000)
//   sarr  floats [60000, 90000)    = bytes [240000, 360000)   (fp32 fallback only)
//   part  floats [90000, 92560)    = bytes [360000, 370240)   (K1_BLOCKS x 5)
//   inv   floats [92560, 122560)   = bytes [370240, 490240)   (fp32 fallback only)
//   nvis  bytes  [524288, 31244288)                            (fp16 rows, 1024 B/row)
//   -> no overlaps; total need 31.25 MB
#define ACC_OFF  0
#define DEG_OFF  30000
#define SARR_OFF 60000
#define PART_OFF 90000
#define INV_OFF  92560
#define NV_BYTE_OFF 524288u

__device__ inline float2 h2f(unsigned int u) {
    const __half2 h = *reinterpret_cast<const __half2*>(&u);
    return __half22float2(h);
}

// ================= K1: zero acc/deg + moment partials + normalize (R10-proven) =====
__global__ void __launch_bounds__(256) k1_prep(
        const float* __restrict__ x,
        const float* __restrict__ visual,
        float* __restrict__ ws, int fp16mode) {
    const int t      = threadIdx.x;
    const int gid    = blockIdx.x * blockDim.x + t;
    const int stride = gridDim.x * blockDim.x;
    const int lane   = t & 63;

    // --- zero acc + deg ---
    for (int i = gid; i < 2 * N_NODES; i += stride) ws[i] = 0.f;

    // --- per-block moment partials of x ---
    {
        __shared__ float red[4][5];
        float s0 = 0.f, s1 = 0.f, s00 = 0.f, s11 = 0.f, s01 = 0.f;
        for (int i = gid; i < N_NODES; i += stride) {
            float2 v = ((const float2*)x)[i];
            s0  += v.x;       s1  += v.y;
            s00 += v.x * v.x; s11 += v.y * v.y;
            s01 += v.x * v.y;
        }
        for (int o = 32; o; o >>= 1) {
            s0  += __shfl_xor(s0,  o, 64);
            s1  += __shfl_xor(s1,  o, 64);
            s00 += __shfl_xor(s00, o, 64);
            s11 += __shfl_xor(s11, o, 64);
            s01 += __shfl_xor(s01, o, 64);
        }
        int wv = t >> 6;
        if (lane == 0) {
            red[wv][0] = s0; red[wv][1] = s1; red[wv][2] = s00;
            red[wv][3] = s11; red[wv][4] = s01;
        }
        __syncthreads();
        if (t < 5) {
            ws[PART_OFF + blockIdx.x * 5 + t] =
                red[0][t] + red[1][t] + red[2][t] + red[3][t];
        }
    }

    // --- normalize visual rows (wave per node) ---
    ushort* nvis = (ushort*)((char*)ws + NV_BYTE_OFF);
    float*  inv  = ws + INV_OFF;
    int wave  = gid >> 6;
    int nwave = stride >> 6;
    for (int node = wave; node < N_NODES; node += nwave) {
        const float4* row = (const float4*)(visual + (size_t)node * VD);
        float4 a = row[lane];
        float4 b = row[lane + 64];
        float p = a.x*a.x + a.y*a.y + a.z*a.z + a.w*a.w
                + b.x*b.x + b.y*b.y + b.z*b.z + b.w*b.w;
        for (int o = 32; o; o >>= 1) p += __shfl_xor(p, o, 64);
        float r = 1.0f / fmaxf(sqrtf(p), 1e-8f);
        if (fp16mode) {
            __half2 p0 = __floats2half2_rn(a.x * r, a.y * r);
            __half2 p1 = __floats2half2_rn(a.z * r, a.w * r);
            __half2 p2 = __floats2half2_rn(b.x * r, b.y * r);
            __half2 p3 = __floats2half2_rn(b.z * r, b.w * r);
            uint2 q0, q1;
            q0.x = *(unsigned int*)&p0; q0.y = *(unsigned int*)&p1;
            q1.x = *(unsigned int*)&p2; q1.y = *(unsigned int*)&p3;
            uint2* orow = (uint2*)(nvis + (size_t)node * VD);
            orow[lane]      = q0;
            orow[lane + 64] = q1;
        } else if (lane == 0) {
            inv[node] = r;
        }
    }
}

// ===== K3: edge kernel; per-block prologue folds partials -> BN scalars in LDS;
//           sarr computed on the fly per staged edge (x is L2-resident, 240 KB) =====
__global__ void __launch_bounds__(256) k3_edge16(
        const int* __restrict__ ei,
        const float* __restrict__ x,
        const float* __restrict__ w1, const float* __restrict__ b1,
        const float* __restrict__ gamma, const float* __restrict__ beta,
        const float* __restrict__ prelu_a,
        const float* __restrict__ w2, const float* __restrict__ b2,
        const float* __restrict__ wc, const float* __restrict__ wp,
        const float* __restrict__ ws_ro,
        float* __restrict__ acc,
        float* __restrict__ deg) {
    __shared__ float red[4][5];
    __shared__ float s_S[5];
    __shared__ float s_scale[HID], s_shift[HID], s_u[HID], s_w1a[HID], s_w1b[HID], s_b1[HID];
    __shared__ float s_wpc[HID];
    __shared__ float s_sb;
    const uint4* nvis = (const uint4*)((const char*)ws_ro + NV_BYTE_OFF);
    const float* part = ws_ro + PART_OFF;
    const int t    = threadIdx.x;
    const int lane = t & 63;

    // --- prologue: fold partials (bit-identical to R10's k2 fold) ---
    {
        float S[5] = {0.f, 0.f, 0.f, 0.f, 0.f};
        for (int j = t; j < K1_BLOCKS; j += 256) {
            #pragma unroll
            for (int c = 0; c < 5; ++c) S[c] += part[j * 5 + c];
        }
        #pragma unroll
        for (int c = 0; c < 5; ++c)
            for (int o = 32; o; o >>= 1) S[c] += __shfl_xor(S[c], o, 64);
        int wv = t >> 6;
        if (lane == 0) {
            #pragma unroll
            for (int c = 0; c < 5; ++c) red[wv][c] = S[c];
        }
        __syncthreads();
        if (t < 5) s_S[t] = red[0][t] + red[1][t] + red[2][t] + red[3][t];
        __syncthreads();
    }
    if (t < HID) {
        float wpck = 0.f;
        for (int j = 0; j < HID; ++j) wpck += wp[j] * wc[j * HID + t];
        s_wpc[t] = wpck;
        const float invN = 1.0f / (float)N_NODES;
        float m0  = s_S[0] * invN, m1 = s_S[1] * invN;
        float v0  = fmaxf(s_S[2] * invN - m0 * m0, 0.f);
        float v1  = fmaxf(s_S[3] * invN - m1 * m1, 0.f);
        float c01 = s_S[4] * invN - m0 * m1;
        float a0 = w1[2 * t], a1 = w1[2 * t + 1];
        float mean = a0 * m0 + a1 * m1 + b1[t];
        float var  = fmaxf(a0 * a0 * v0 + a1 * a1 * v1 + 2.f * a0 * a1 * c01, 0.f);
        float rs    = 1.0f / sqrtf(var + 1e-5f);
        float scale = gamma[t] * rs;
        s_scale[t] = scale;
        s_shift[t] = beta[t] - mean * scale;
        s_w1a[t] = a0; s_w1b[t] = a1;
        s_b1[t]  = b1[t];
    }
    __syncthreads();
    if (t < HID) {
        float uu = 0.f;
        for (int k = 0; k < HID; ++k) uu += s_wpc[k] * w2[k * HID + t];
        s_u[t] = uu;
    }
    if (t == 0) {
        float sb = 0.f;
        for (int k = 0; k < HID; ++k) sb += s_wpc[k] * b2[k];
        s_sb = sb;
    }
    __syncthreads();
    const float aslope = prelu_a[0];
    const float sb = s_sb;

    // --- edge loop (R8/R10-proven structure, x2 unroll) ---
    const int r    = blockIdx.x & 7;                       // src-bucket residue -> XCD
    const int q    = (blockIdx.x >> 3) * (blockDim.x >> 6) + (t >> 6);
    const int nq   = (gridDim.x >> 3) * (blockDim.x >> 6);
    const int nchunk = E_EDGES >> 6;                       // 7500 (exact)

    for (int c = q; c < nchunk; c += nq) {
        int idx = (c << 6) + lane;
        int s = ei[idx];
        int d = ei[E_EDGES + idx];
        bool mine = (s / BUCKET == r);
        float mys = 0.f;
        if (mine) {
            float2 xv = ((const float2*)x)[s];
            float sacc = sb;
            #pragma unroll
            for (int cc = 0; cc < HID; ++cc) {
                float h  = s_w1a[cc] * xv.x + s_w1b[cc] * xv.y + s_b1[cc];
                float tt = h * s_scale[cc] + s_shift[cc];
                tt = tt >= 0.f ? tt : aslope * tt;
                sacc += tt * s_u[cc];
            }
            mys = sacc;
        }
        unsigned long long m = __ballot(mine);
        while (m) {
            int j1 = __ffsll(m) - 1;
            m &= m - 1;
            bool two = (m != 0);
            int j2 = j1;
            if (two) { j2 = __ffsll(m) - 1; m &= m - 1; }
            int   sj1 = __shfl(s, j1, 64), dj1 = __shfl(d, j1, 64);
            int   sj2 = __shfl(s, j2, 64), dj2 = __shfl(d, j2, 64);
            float sv1 = __shfl(mys, j1, 64), sv2 = __shfl(mys, j2, 64);
            uint4 A1 = nvis[(size_t)sj1 * 64 + lane];
            uint4 B1 = nvis[(size_t)dj1 * 64 + lane];
            uint4 A2 = nvis[(size_t)sj2 * 64 + lane];
            uint4 B2 = nvis[(size_t)dj2 * 64 + lane];
            float2 a0 = h2f(A1.x), a1 = h2f(A1.y), a2 = h2f(A1.z), a3 = h2f(A1.w);
            float2 b0 = h2f(B1.x), b1v = h2f(B1.y), b2v = h2f(B1.z), b3 = h2f(B1.w);
            float p1 = a0.x*b0.x + a0.y*b0.y + a1.x*b1v.x + a1.y*b1v.y
                     + a2.x*b2v.x + a2.y*b2v.y + a3.x*b3.x + a3.y*b3.y;
            float2 c0 = h2f(A2.x), c1 = h2f(A2.y), c2 = h2f(A2.z), c3 = h2f(A2.w);
            float2 e0 = h2f(B2.x), e1 = h2f(B2.y), e2 = h2f(B2.z), e3 = h2f(B2.w);
            float p2 = c0.x*e0.x + c0.y*e0.y + c1.x*e1.x + c1.y*e1.y
                     + c2.x*e2.x + c2.y*e2.y + c3.x*e3.x + c3.y*e3.y;
            #pragma unroll
            for (int o = 32; o; o >>= 1) {
                p1 += __shfl_xor(p1, o, 64);
                p2 += __shfl_xor(p2, o, 64);
            }
            if (lane == 0) {
                atomicAdd(&acc[dj1], p1 * sv1);
                atomicAdd(&deg[dj1], 1.0f);
                if (two) {
                    atomicAdd(&acc[dj2], p2 * sv2);
                    atomicAdd(&deg[dj2], 1.0f);
                }
            }
        }
    }
}

// ================= fp32 fallback path (4 dispatches, R10 structure) =================
__global__ void __launch_bounds__(256) k2_sarr(
        const float* __restrict__ x,
        const float* __restrict__ w1, const float* __restrict__ b1,
        const float* __restrict__ gamma, const float* __restrict__ beta,
        const float* __restrict__ prelu_a,
        const float* __restrict__ w2, const float* __restrict__ b2,
        const float* __restrict__ wc, const float* __restrict__ wp,
        const float* __restrict__ ws_ro,
        float* __restrict__ sarr) {
    __shared__ float red[4][5];
    __shared__ float s_S[5];
    __shared__ float s_scale[HID], s_shift[HID], s_u[HID], s_w1a[HID], s_w1b[HID];
    __shared__ float s_wpc[HID];
    __shared__ float s_sb;
    const float* part = ws_ro + PART_OFF;
    const int t    = threadIdx.x;
    const int lane = t & 63;
    {
        float S[5] = {0.f, 0.f, 0.f, 0.f, 0.f};
        for (int j = t; j < K1_BLOCKS; j += 256) {
            #pragma unroll
            for (int c = 0; c < 5; ++c) S[c] += part[j * 5 + c];
        }
        #pragma unroll
        for (int c = 0; c < 5; ++c)
            for (int o = 32; o; o >>= 1) S[c] += __shfl_xor(S[c], o, 64);
        int wv = t >> 6;
        if (lane == 0) {
            #pragma unroll
            for (int c = 0; c < 5; ++c) red[wv][c] = S[c];
        }
        __syncthreads();
        if (t < 5) s_S[t] = red[0][t] + red[1][t] + red[2][t] + red[3][t];
        __syncthreads();
    }
    if (t < HID) {
        float wpck = 0.f;
        for (int j = 0; j < HID; ++j) wpck += wp[j] * wc[j * HID + t];
        s_wpc[t] = wpck;
        const float invN = 1.0f / (float)N_NODES;
        float m0  = s_S[0] * invN, m1 = s_S[1] * invN;
        float v0  = fmaxf(s_S[2] * invN - m0 * m0, 0.f);
        float v1  = fmaxf(s_S[3] * invN - m1 * m1, 0.f);
        float c01 = s_S[4] * invN - m0 * m1;
        float a0 = w1[2 * t], a1 = w1[2 * t + 1];
        float mean = a0 * m0 + a1 * m1 + b1[t];
        float var  = fmaxf(a0 * a0 * v0 + a1 * a1 * v1 + 2.f * a0 * a1 * c01, 0.f);
        float rs    = 1.0f / sqrtf(var + 1e-5f);
        float scale = gamma[t] * rs;
        s_scale[t] = scale;
        s_shift[t] = beta[t] - mean * scale;
        s_w1a[t] = a0; s_w1b[t] = a1;
    }
    __syncthreads();
    if (t < HID) {
        float uu = 0.f;
        for (int k = 0; k < HID; ++k) uu += s_wpc[k] * w2[k * HID + t];
        s_u[t] = uu;
    }
    if (t == 0) {
        float sb = 0.f;
        for (int k = 0; k < HID; ++k) sb += s_wpc[k] * b2[k];
        s_sb = sb;
    }
    __syncthreads();
    const float aslope = prelu_a[0];
    const float sb = s_sb;
    for (int i = blockIdx.x * blockDim.x + t; i < N_NODES; i += gridDim.x * blockDim.x) {
        float2 xv = ((const float2*)x)[i];
        float sacc = sb;
        #pragma unroll
        for (int c = 0; c < HID; ++c) {
            float h  = s_w1a[c] * xv.x + s_w1b[c] * xv.y + b1[c];
            float tt = h * s_scale[c] + s_shift[c];
            tt = tt >= 0.f ? tt : aslope * tt;
            sacc += tt * s_u[c];
        }
        sarr[i] = sacc;
    }
}

__global__ void __launch_bounds__(256) k3_edge32(const int* __restrict__ ei,
                                                 const float* __restrict__ visual,
                                                 const float* __restrict__ inv,
                                                 const float* __restrict__ sarr,
                                                 float* __restrict__ acc,
                                                 float* __restrict__ deg) {
    int wave  = (blockIdx.x * blockDim.x + threadIdx.x) >> 6;
    int lane  = threadIdx.x & 63;
    int nwave = (gridDim.x * blockDim.x) >> 6;
    for (int e = wave; e < E_EDGES; e += nwave) {
        int s = ei[e];
        int d = ei[E_EDGES + e];
        const float4* ra = (const float4*)(visual + (size_t)s * VD);
        const float4* rb = (const float4*)(visual + (size_t)d * VD);
        float4 a0 = ra[lane];
        float4 b0 = rb[lane];
        float4 a1 = ra[lane + 64];
        float4 b1 = rb[lane + 64];
        float p = a0.x*b0.x + a0.y*b0.y + a0.z*b0.z + a0.w*b0.w
                + a1.x*b1.x + a1.y*b1.y + a1.z*b1.z + a1.w*b1.w;
        for (int o = 32; o; o >>= 1) p += __shfl_xor(p, o, 64);
        if (lane == 0) {
            float w = p * inv[s] * inv[d];
            atomicAdd(&acc[d], w * sarr[s]);
            atomicAdd(&deg[d], 1.0f);
        }
    }
}

// ================= K4: final =================
__global__ void k4_final(const float* __restrict__ acc, const float* __restrict__ deg,
                         const float* __restrict__ bc, const float* __restrict__ wp,
                         const float* __restrict__ bp, float* __restrict__ out, int n) {
    float K = bp[0];
    #pragma unroll
    for (int j = 0; j < HID; ++j) K += wp[j] * bc[j];
    for (int i = blockIdx.x * blockDim.x + threadIdx.x; i < n; i += gridDim.x * blockDim.x) {
        out[i] = acc[i] / fmaxf(deg[i], 1.0f) + K;
    }
}

extern "C" void kernel_launch(void* const* d_in, const int* in_sizes, int n_in,
                              void* d_out, int out_size, void* d_ws, size_t ws_size,
                              hipStream_t stream) {
    const float* x       = (const float*)d_in[0];
    const float* visual  = (const float*)d_in[1];
    const int*   ei      = (const int*)  d_in[2];
    const float* w1      = (const float*)d_in[3];
    const float* b1      = (const float*)d_in[4];
    const float* gamma   = (const float*)d_in[5];
    const float* beta    = (const float*)d_in[6];
    const float* prelu_a = (const float*)d_in[7];
    const float* w2      = (const float*)d_in[8];
    const float* b2      = (const float*)d_in[9];
    const float* wc      = (const float*)d_in[10];
    const float* bc      = (const float*)d_in[11];
    const float* wp      = (const float*)d_in[12];
    const float* bp      = (const float*)d_in[13];
    float* out = (float*)d_out;

    float* ws   = (float*)d_ws;
    float* acc  = ws + ACC_OFF;
    float* deg  = ws + DEG_OFF;
    float* sarr = ws + SARR_OFF;
    float* inv  = ws + INV_OFF;

    bool fp16ok = ws_size >= (size_t)NV_BYTE_OFF + (size_t)N_NODES * VD * 2;

    k1_prep<<<K1_BLOCKS, 256, 0, stream>>>(x, visual, ws, fp16ok ? 1 : 0);
    if (fp16ok) {
        k3_edge16<<<4096, 256, 0, stream>>>(ei, x, w1, b1, gamma, beta, prelu_a,
                                            w2, b2, wc, wp, ws, acc, deg);
    } else {
        k2_sarr<<<256, 256, 0, stream>>>(x, w1, b1, gamma, beta, prelu_a, w2, b2,
                                         wc, wp, ws, sarr);
        k3_edge32<<<4096, 256, 0, stream>>>(ei, visual, inv, sarr, acc, deg);
    }
    k4_final<<<120, 256, 0, stream>>>(acc, deg, bc, wp, bp, out, N_NODES);
}

// Round 12
// 235.122 us; speedup vs baseline: 1.4685x; 1.4685x over previous
//
#include <hip/hip_runtime.h>
#include <hip/hip_fp16.h>
#include <math.h>

#define N_NODES 30000
#define E_EDGES 480000
#define VD      512
#define HID     32
#define BUCKET  3750   // rows per src-bucket: 3750 * 1KB = 3.75 MB < 4 MB per-XCD L2
#define K1_BLOCKS 512

// ws layout — BYTE-INTERVAL AUDIT (4-byte floats unless noted):
//   acc   floats [0, 30000)        = bytes [0, 120000)
//   deg   floats [30000, 60000)    = bytes [120000, 240000)
//   sarr  floats [60000, 90000)    = bytes [240000, 360000)
//   part  floats [90000, 92560)    = bytes [360000, 370240)   (K1_BLOCKS x 5)
//   inv   floats [92560, 122560)   = bytes [370240, 490240)   (fp32 fallback only)
//   nvis  bytes  [524288, 31244288)                            (fp16 rows, 1024 B/row)
//   -> no overlaps; total need 31.25 MB
#define ACC_OFF  0
#define DEG_OFF  30000
#define SARR_OFF 60000
#define PART_OFF 90000
#define INV_OFF  92560
#define NV_BYTE_OFF 524288u

__device__ inline float2 h2f(unsigned int u) {
    const __half2 h = *reinterpret_cast<const __half2*>(&u);
    return __half22float2(h);
}

// ================= K1: zero acc/deg + moment partials + normalize (R10-proven) =====
__global__ void __launch_bounds__(256) k1_prep(
        const float* __restrict__ x,
        const float* __restrict__ visual,
        float* __restrict__ ws, int fp16mode) {
    const int t      = threadIdx.x;
    const int gid    = blockIdx.x * blockDim.x + t;
    const int stride = gridDim.x * blockDim.x;
    const int lane   = t & 63;

    // --- zero acc + deg ---
    for (int i = gid; i < 2 * N_NODES; i += stride) ws[i] = 0.f;

    // --- per-block moment partials of x ---
    {
        __shared__ float red[4][5];
        float s0 = 0.f, s1 = 0.f, s00 = 0.f, s11 = 0.f, s01 = 0.f;
        for (int i = gid; i < N_NODES; i += stride) {
            float2 v = ((const float2*)x)[i];
            s0  += v.x;       s1  += v.y;
            s00 += v.x * v.x; s11 += v.y * v.y;
            s01 += v.x * v.y;
        }
        for (int o = 32; o; o >>= 1) {
            s0  += __shfl_xor(s0,  o, 64);
            s1  += __shfl_xor(s1,  o, 64);
            s00 += __shfl_xor(s00, o, 64);
            s11 += __shfl_xor(s11, o, 64);
            s01 += __shfl_xor(s01, o, 64);
        }
        int wv = t >> 6;
        if (lane == 0) {
            red[wv][0] = s0; red[wv][1] = s1; red[wv][2] = s00;
            red[wv][3] = s11; red[wv][4] = s01;
        }
        __syncthreads();
        if (t < 5) {
            ws[PART_OFF + blockIdx.x * 5 + t] =
                red[0][t] + red[1][t] + red[2][t] + red[3][t];
        }
    }

    // --- normalize visual rows (wave per node) ---
    ushort* nvis = (ushort*)((char*)ws + NV_BYTE_OFF);
    float*  inv  = ws + INV_OFF;
    int wave  = gid >> 6;
    int nwave = stride >> 6;
    for (int node = wave; node < N_NODES; node += nwave) {
        const float4* row = (const float4*)(visual + (size_t)node * VD);
        float4 a = row[lane];
        float4 b = row[lane + 64];
        float p = a.x*a.x + a.y*a.y + a.z*a.z + a.w*a.w
                + b.x*b.x + b.y*b.y + b.z*b.z + b.w*b.w;
        for (int o = 32; o; o >>= 1) p += __shfl_xor(p, o, 64);
        float r = 1.0f / fmaxf(sqrtf(p), 1e-8f);
        if (fp16mode) {
            __half2 p0 = __floats2half2_rn(a.x * r, a.y * r);
            __half2 p1 = __floats2half2_rn(a.z * r, a.w * r);
            __half2 p2 = __floats2half2_rn(b.x * r, b.y * r);
            __half2 p3 = __floats2half2_rn(b.z * r, b.w * r);
            uint2 q0, q1;
            q0.x = *(unsigned int*)&p0; q0.y = *(unsigned int*)&p1;
            q1.x = *(unsigned int*)&p2; q1.y = *(unsigned int*)&p3;
            uint2* orow = (uint2*)(nvis + (size_t)node * VD);
            orow[lane]      = q0;
            orow[lane + 64] = q1;
        } else if (lane == 0) {
            inv[node] = r;
        }
    }
}

// ================= K2: parallel fold of partials + BN scalars + sarr (R10-proven) ====
__global__ void __launch_bounds__(256) k2_sarr(
        const float* __restrict__ x,
        const float* __restrict__ w1, const float* __restrict__ b1,
        const float* __restrict__ gamma, const float* __restrict__ beta,
        const float* __restrict__ prelu_a,
        const float* __restrict__ w2, const float* __restrict__ b2,
        const float* __restrict__ wc, const float* __restrict__ wp,
        const float* __restrict__ ws_ro,
        float* __restrict__ sarr) {
    __shared__ float red[4][5];
    __shared__ float s_S[5];
    __shared__ float s_scale[HID], s_shift[HID], s_u[HID], s_w1a[HID], s_w1b[HID];
    __shared__ float s_wpc[HID];
    __shared__ float s_sb;
    const float* part = ws_ro + PART_OFF;
    const int t    = threadIdx.x;
    const int lane = t & 63;

    {
        float S[5] = {0.f, 0.f, 0.f, 0.f, 0.f};
        for (int j = t; j < K1_BLOCKS; j += 256) {
            #pragma unroll
            for (int c = 0; c < 5; ++c) S[c] += part[j * 5 + c];
        }
        #pragma unroll
        for (int c = 0; c < 5; ++c)
            for (int o = 32; o; o >>= 1) S[c] += __shfl_xor(S[c], o, 64);
        int wv = t >> 6;
        if (lane == 0) {
            #pragma unroll
            for (int c = 0; c < 5; ++c) red[wv][c] = S[c];
        }
        __syncthreads();
        if (t < 5) s_S[t] = red[0][t] + red[1][t] + red[2][t] + red[3][t];
        __syncthreads();
    }

    if (t < HID) {
        float wpck = 0.f;
        for (int j = 0; j < HID; ++j) wpck += wp[j] * wc[j * HID + t];
        s_wpc[t] = wpck;
        const float invN = 1.0f / (float)N_NODES;
        float m0  = s_S[0] * invN, m1 = s_S[1] * invN;
        float v0  = fmaxf(s_S[2] * invN - m0 * m0, 0.f);
        float v1  = fmaxf(s_S[3] * invN - m1 * m1, 0.f);
        float c01 = s_S[4] * invN - m0 * m1;
        float a0 = w1[2 * t], a1 = w1[2 * t + 1];
        float mean = a0 * m0 + a1 * m1 + b1[t];
        float var  = fmaxf(a0 * a0 * v0 + a1 * a1 * v1 + 2.f * a0 * a1 * c01, 0.f);
        float rs    = 1.0f / sqrtf(var + 1e-5f);
        float scale = gamma[t] * rs;
        s_scale[t] = scale;
        s_shift[t] = beta[t] - mean * scale;
        s_w1a[t] = a0; s_w1b[t] = a1;
    }
    __syncthreads();
    if (t < HID) {
        float uu = 0.f;
        for (int k = 0; k < HID; ++k) uu += s_wpc[k] * w2[k * HID + t];
        s_u[t] = uu;
    }
    if (t == 0) {
        float sb = 0.f;
        for (int k = 0; k < HID; ++k) sb += s_wpc[k] * b2[k];
        s_sb = sb;
    }
    __syncthreads();
    const float aslope = prelu_a[0];
    const float sb = s_sb;
    for (int i = blockIdx.x * blockDim.x + t; i < N_NODES; i += gridDim.x * blockDim.x) {
        float2 xv = ((const float2*)x)[i];
        float sacc = sb;
        #pragma unroll
        for (int c = 0; c < HID; ++c) {
            float h  = s_w1a[c] * xv.x + s_w1b[c] * xv.y + b1[c];
            float tt = h * s_scale[c] + s_shift[c];
            tt = tt >= 0.f ? tt : aslope * tt;
            sacc += tt * s_u[c];
        }
        sarr[i] = sacc;
    }
}

// ===== K3: src-bucketed skip-scan edge kernel, mask-loop unrolled x4 =====
__global__ void __launch_bounds__(256) k3_edge16(const int* __restrict__ ei,
                                                 const float* __restrict__ ws_ro,
                                                 float* __restrict__ acc,
                                                 float* __restrict__ deg,
                                                 const float* __restrict__ sarr) {
    const uint4* nvis = (const uint4*)((const char*)ws_ro + NV_BYTE_OFF);
    const int lane = threadIdx.x & 63;
    const int r    = blockIdx.x & 7;                       // src-bucket residue -> XCD
    const int q    = (blockIdx.x >> 3) * (blockDim.x >> 6) + (threadIdx.x >> 6);
    const int nq   = (gridDim.x >> 3) * (blockDim.x >> 6);
    const int nchunk = E_EDGES >> 6;                       // 7500 (exact)

    for (int c = q; c < nchunk; c += nq) {
        int idx = (c << 6) + lane;
        int s = ei[idx];
        int d = ei[E_EDGES + idx];
        bool mine = (s / BUCKET == r);
        float mys = mine ? sarr[s] : 0.f;
        unsigned long long m = __ballot(mine);
        while (m) {
            // extract up to 4 set bits; inactive slots duplicate slot 0
            int j0 = __ffsll(m) - 1;  m &= m - 1;
            int cnt = 1;
            int j1 = j0, j2 = j0, j3 = j0;
            if (m) { j1 = __ffsll(m) - 1; m &= m - 1; cnt = 2; }
            if (m) { j2 = __ffsll(m) - 1; m &= m - 1; cnt = 3; }
            if (m) { j3 = __ffsll(m) - 1; m &= m - 1; cnt = 4; }

            int sj0 = __shfl(s, j0, 64), dj0 = __shfl(d, j0, 64);
            int sj1 = __shfl(s, j1, 64), dj1 = __shfl(d, j1, 64);
            int sj2 = __shfl(s, j2, 64), dj2 = __shfl(d, j2, 64);
            int sj3 = __shfl(s, j3, 64), dj3 = __shfl(d, j3, 64);
            float sv0 = __shfl(mys, j0, 64), sv1 = __shfl(mys, j1, 64);
            float sv2 = __shfl(mys, j2, 64), sv3 = __shfl(mys, j3, 64);

            uint4 A0 = nvis[(size_t)sj0 * 64 + lane];
            uint4 B0 = nvis[(size_t)dj0 * 64 + lane];
            uint4 A1 = nvis[(size_t)sj1 * 64 + lane];
            uint4 B1 = nvis[(size_t)dj1 * 64 + lane];
            uint4 A2 = nvis[(size_t)sj2 * 64 + lane];
            uint4 B2 = nvis[(size_t)dj2 * 64 + lane];
            uint4 A3 = nvis[(size_t)sj3 * 64 + lane];
            uint4 B3 = nvis[(size_t)dj3 * 64 + lane];

            float2 u0, v0;
            float p0 = 0.f, p1 = 0.f, p2 = 0.f, p3 = 0.f;
            u0 = h2f(A0.x); v0 = h2f(B0.x); p0 += u0.x*v0.x + u0.y*v0.y;
            u0 = h2f(A0.y); v0 = h2f(B0.y); p0 += u0.x*v0.x + u0.y*v0.y;
            u0 = h2f(A0.z); v0 = h2f(B0.z); p0 += u0.x*v0.x + u0.y*v0.y;
            u0 = h2f(A0.w); v0 = h2f(B0.w); p0 += u0.x*v0.x + u0.y*v0.y;
            u0 = h2f(A1.x); v0 = h2f(B1.x); p1 += u0.x*v0.x + u0.y*v0.y;
            u0 = h2f(A1.y); v0 = h2f(B1.y); p1 += u0.x*v0.x + u0.y*v0.y;
            u0 = h2f(A1.z); v0 = h2f(B1.z); p1 += u0.x*v0.x + u0.y*v0.y;
            u0 = h2f(A1.w); v0 = h2f(B1.w); p1 += u0.x*v0.x + u0.y*v0.y;
            u0 = h2f(A2.x); v0 = h2f(B2.x); p2 += u0.x*v0.x + u0.y*v0.y;
            u0 = h2f(A2.y); v0 = h2f(B2.y); p2 += u0.x*v0.x + u0.y*v0.y;
            u0 = h2f(A2.z); v0 = h2f(B2.z); p2 += u0.x*v0.x + u0.y*v0.y;
            u0 = h2f(A2.w); v0 = h2f(B2.w); p2 += u0.x*v0.x + u0.y*v0.y;
            u0 = h2f(A3.x); v0 = h2f(B3.x); p3 += u0.x*v0.x + u0.y*v0.y;
            u0 = h2f(A3.y); v0 = h2f(B3.y); p3 += u0.x*v0.x + u0.y*v0.y;
            u0 = h2f(A3.z); v0 = h2f(B3.z); p3 += u0.x*v0.x + u0.y*v0.y;
            u0 = h2f(A3.w); v0 = h2f(B3.w); p3 += u0.x*v0.x + u0.y*v0.y;

            #pragma unroll
            for (int o = 32; o; o >>= 1) {
                p0 += __shfl_xor(p0, o, 64);
                p1 += __shfl_xor(p1, o, 64);
                p2 += __shfl_xor(p2, o, 64);
                p3 += __shfl_xor(p3, o, 64);
            }
            if (lane == 0) {
                atomicAdd(&acc[dj0], p0 * sv0);
                atomicAdd(&deg[dj0], 1.0f);
                if (cnt > 1) { atomicAdd(&acc[dj1], p1 * sv1); atomicAdd(&deg[dj1], 1.0f); }
                if (cnt > 2) { atomicAdd(&acc[dj2], p2 * sv2); atomicAdd(&deg[dj2], 1.0f); }
                if (cnt > 3) { atomicAdd(&acc[dj3], p3 * sv3); atomicAdd(&deg[dj3], 1.0f); }
            }
        }
    }
}

// fp32 fallback edge kernel (correctness path)
__global__ void __launch_bounds__(256) k3_edge32(const int* __restrict__ ei,
                                                 const float* __restrict__ visual,
                                                 const float* __restrict__ inv,
                                                 const float* __restrict__ sarr,
                                                 float* __restrict__ acc,
                                                 float* __restrict__ deg) {
    int wave  = (blockIdx.x * blockDim.x + threadIdx.x) >> 6;
    int lane  = threadIdx.x & 63;
    int nwave = (gridDim.x * blockDim.x) >> 6;
    for (int e = wave; e < E_EDGES; e += nwave) {
        int s = ei[e];
        int d = ei[E_EDGES + e];
        const float4* ra = (const float4*)(visual + (size_t)s * VD);
        const float4* rb = (const float4*)(visual + (size_t)d * VD);
        float4 a0 = ra[lane];
        float4 b0 = rb[lane];
        float4 a1 = ra[lane + 64];
        float4 b1 = rb[lane + 64];
        float p = a0.x*b0.x + a0.y*b0.y + a0.z*b0.z + a0.w*b0.w
                + a1.x*b1.x + a1.y*b1.y + a1.z*b1.z + a1.w*b1.w;
        for (int o = 32; o; o >>= 1) p += __shfl_xor(p, o, 64);
        if (lane == 0) {
            float w = p * inv[s] * inv[d];
            atomicAdd(&acc[d], w * sarr[s]);
            atomicAdd(&deg[d], 1.0f);
        }
    }
}

// ================= K4: final =================
__global__ void k4_final(const float* __restrict__ acc, const float* __restrict__ deg,
                         const float* __restrict__ bc, const float* __restrict__ wp,
                         const float* __restrict__ bp, float* __restrict__ out, int n) {
    float K = bp[0];
    #pragma unroll
    for (int j = 0; j < HID; ++j) K += wp[j] * bc[j];
    for (int i = blockIdx.x * blockDim.x + threadIdx.x; i < n; i += gridDim.x * blockDim.x) {
        out[i] = acc[i] / fmaxf(deg[i], 1.0f) + K;
    }
}

extern "C" void kernel_launch(void* const* d_in, const int* in_sizes, int n_in,
                              void* d_out, int out_size, void* d_ws, size_t ws_size,
                              hipStream_t stream) {
    const float* x       = (const float*)d_in[0];
    const float* visual  = (const float*)d_in[1];
    const int*   ei      = (const int*)  d_in[2];
    const float* w1      = (const float*)d_in[3];
    const float* b1      = (const float*)d_in[4];
    const float* gamma   = (const float*)d_in[5];
    const float* beta    = (const float*)d_in[6];
    const float* prelu_a = (const float*)d_in[7];
    const float* w2      = (const float*)d_in[8];
    const float* b2      = (const float*)d_in[9];
    const float* wc      = (const float*)d_in[10];
    const float* bc      = (const float*)d_in[11];
    const float* wp      = (const float*)d_in[12];
    const float* bp      = (const float*)d_in[13];
    float* out = (float*)d_out;

    float* ws   = (float*)d_ws;
    float* acc  = ws + ACC_OFF;
    float* deg  = ws + DEG_OFF;
    float* sarr = ws + SARR_OFF;
    float* inv  = ws + INV_OFF;

    bool fp16ok = ws_size >= (size_t)NV_BYTE_OFF + (size_t)N_NODES * VD * 2;

    k1_prep<<<K1_BLOCKS, 256, 0, stream>>>(x, visual, ws, fp16ok ? 1 : 0);
    k2_sarr<<<256, 256, 0, stream>>>(x, w1, b1, gamma, beta, prelu_a, w2, b2, wc, wp,
                                     ws, sarr);
    if (fp16ok) {
        k3_edge16<<<4096, 256, 0, stream>>>(ei, ws, acc, deg, sarr);
    } else {
        k3_edge32<<<4096, 256, 0, stream>>>(ei, visual, inv, sarr, acc, deg);
    }
    k4_final<<<120, 256, 0, stream>>>(acc, deg, bc, wp, bp, out, N_NODES);
}